// Round 1
// baseline (4353.954 us; speedup 1.0000x reference)
//
#include <hip/hip_runtime.h>
#include <math.h>

// ---------------------------------------------------------------------------
// GCN (3 layers, PyG GCNConv w/ self-loops) + global attention pooling.
// N=100000 nodes, E=1600000 edges, D: 128 -> 64 -> 64 -> 64.
//
// Strategy (round 1: correctness + baseline profile):
//   deg/dinv  : atomic count per dst, then rsqrt
//   GEMM      : fp32 vector-ALU, 64-row x 64-col block, 4x4 register tile,
//               LDS A (swizzled) + LDS W^T (swizzled), bias+ReLU fused on load
//   aggregate : init agg = h*dinv^2 (self loop), then edge-parallel atomicAdd
//               scatter (16 threads/edge, float4 gather of h[src])
//   attention : per-node 64x64 matvec + tanh + dot(q) -> score;
//               2-stage max; exp-sum + sum(e_i * z_i) via block reduce+atomics
// ---------------------------------------------------------------------------

// ---- edge dtype detection (reference says int64; JAX w/o x64 gives int32) --
__global__ void detect_i64_kernel(const int* __restrict__ ei, int* __restrict__ flag) {
    if (threadIdx.x == 0 && blockIdx.x == 0) {
        int is64 = 1;
        for (int i = 1; i < 512; i += 2)
            if (ei[i] != 0) is64 = 0;
        *flag = is64;
    }
}

__device__ __forceinline__ void load_edge(const void* ei, int e, int E, int is64,
                                          int& s, int& d) {
    if (is64) {
        const long long* p = (const long long*)ei;
        s = (int)p[e]; d = (int)p[E + e];
    } else {
        const int* p = (const int*)ei;
        s = p[e]; d = p[E + e];
    }
}

// ---- degree ---------------------------------------------------------------
__global__ void deg_kernel(const void* __restrict__ ei, const int* __restrict__ flag,
                           float* __restrict__ deg, int E) {
    int e = blockIdx.x * 256 + threadIdx.x;
    if (e >= E) return;
    int is64 = *flag;
    int d;
    if (is64) d = (int)((const long long*)ei)[E + e];
    else      d = ((const int*)ei)[E + e];
    atomicAdd(&deg[d], 1.0f);
}

__global__ void dinv_kernel(float* __restrict__ deg, int N) {
    int i = blockIdx.x * 256 + threadIdx.x;
    if (i < N) deg[i] = rsqrtf(deg[i] + 1.0f);
}

// ---- GEMM: out[N,64] = act(in[N,K]) @ W[K,64] ------------------------------
// act = (PRE ? relu(x + bias[k]) : x), bias indexed by input feature k.
// Block: 256 threads -> 64 rows x 64 cols, thread computes 4x4.
template <int K, bool PRE>
__global__ __launch_bounds__(256) void gemm64(const float* __restrict__ in,
                                              const float* __restrict__ Wg,
                                              const float* __restrict__ bias,
                                              float* __restrict__ out, int nrows) {
    constexpr int KQ = K / 4;                // k-quads per row
    __shared__ float Al[64 * K];             // A tile, quad-swizzled by row
    __shared__ float Wt[64 * K];             // W^T [c][k], quad-swizzled by c>>2
    const int t  = threadIdx.x;
    const int rb = blockIdx.x * 64;

    // stage W transposed (+swizzle). Wg is [K][64] row-major.
    for (int qidx = t; qidx < K * 16; qidx += 256) {
        int k  = qidx >> 4;
        int c0 = (qidx & 15) << 2;
        float4 v = *(const float4*)(Wg + k * 64 + c0);
        float vv[4] = {v.x, v.y, v.z, v.w};
#pragma unroll
        for (int j = 0; j < 4; j++) {
            int c  = c0 + j;
            int kq = (k >> 2) ^ ((c >> 2) & 7);
            Wt[(c * KQ + kq) * 4 + (k & 3)] = vv[j];
        }
    }
    // stage A (+bias/relu, +row swizzle)
    for (int qidx = t; qidx < 64 * KQ; qidx += 256) {
        int r  = qidx / KQ;
        int kc = qidx % KQ;
        float4 v = make_float4(0.f, 0.f, 0.f, 0.f);
        int gr = rb + r;
        if (gr < nrows) v = *(const float4*)(in + (size_t)gr * K + (kc << 2));
        if (PRE) {
            v.x = fmaxf(v.x + bias[(kc << 2) + 0], 0.f);
            v.y = fmaxf(v.y + bias[(kc << 2) + 1], 0.f);
            v.z = fmaxf(v.z + bias[(kc << 2) + 2], 0.f);
            v.w = fmaxf(v.w + bias[(kc << 2) + 3], 0.f);
        }
        int sq = r * KQ + (kc ^ (r & 7));
        *(float4*)(&Al[sq * 4]) = v;
    }
    __syncthreads();

    const int tc = t & 15;   // col group (cols tc*4 .. +3)
    const int tr = t >> 4;   // row group (rows tr*4 .. +3)
    float acc[4][4];
#pragma unroll
    for (int i = 0; i < 4; i++)
#pragma unroll
        for (int j = 0; j < 4; j++) acc[i][j] = 0.f;

    for (int kb = 0; kb < KQ; ++kb) {
        float4 a[4], w[4];
#pragma unroll
        for (int i = 0; i < 4; i++) {
            int r = tr * 4 + i;
            a[i] = *(const float4*)(&Al[(r * KQ + (kb ^ (r & 7))) * 4]);
        }
#pragma unroll
        for (int j = 0; j < 4; j++) {
            int c = tc * 4 + j;
            w[j] = *(const float4*)(&Wt[(c * KQ + (kb ^ ((c >> 2) & 7))) * 4]);
        }
#pragma unroll
        for (int i = 0; i < 4; i++)
#pragma unroll
            for (int j = 0; j < 4; j++)
                acc[i][j] += a[i].x * w[j].x + a[i].y * w[j].y +
                             a[i].z * w[j].z + a[i].w * w[j].w;
    }
#pragma unroll
    for (int i = 0; i < 4; i++) {
        int r = rb + tr * 4 + i;
        if (r < nrows) {
            float4 o = make_float4(acc[i][0], acc[i][1], acc[i][2], acc[i][3]);
            *(float4*)(out + (size_t)r * 64 + tc * 4) = o;
        }
    }
}

// ---- agg init: agg = h * dinv^2 (self-loop term) ---------------------------
__global__ void initagg_kernel(const float* __restrict__ h, const float* __restrict__ dinv,
                               float* __restrict__ agg, int nquads) {
    int tid = blockIdx.x * 256 + threadIdx.x;   // over N*16 quads
    if (tid >= nquads) return;
    int r = tid >> 4;
    float di = dinv[r];
    float w = di * di;
    float4 v = *(const float4*)(h + (size_t)tid * 4);
    v.x *= w; v.y *= w; v.z *= w; v.w *= w;
    *(float4*)(agg + (size_t)tid * 4) = v;
}

// ---- edge scatter: agg[dst] += h[src] * dinv[src]*dinv[dst] ----------------
__global__ __launch_bounds__(256) void scatter_kernel(const float* __restrict__ h,
                                                      const float* __restrict__ dinv,
                                                      const void* __restrict__ ei,
                                                      const int* __restrict__ flag,
                                                      float* __restrict__ agg, int E) {
    long long tid = (long long)blockIdx.x * 256 + threadIdx.x;
    int e  = (int)(tid >> 4);
    int ch = (int)(tid & 15);
    if (e >= E) return;
    int s, d;
    load_edge(ei, e, E, *flag, s, d);
    float w = dinv[s] * dinv[d];
    float4 v = *(const float4*)(h + (size_t)s * 64 + ch * 4);
    float* o = agg + (size_t)d * 64 + ch * 4;
    atomicAdd(o + 0, v.x * w);
    atomicAdd(o + 1, v.y * w);
    atomicAdd(o + 2, v.z * w);
    atomicAdd(o + 3, v.w * w);
}

// ---- z += b3 (in place) -----------------------------------------------------
__global__ void biasadd_kernel(float* __restrict__ z, const float* __restrict__ b,
                               int nquads) {
    int tid = blockIdx.x * 256 + threadIdx.x;
    if (tid >= nquads) return;
    float4 v = *(float4*)(z + (size_t)tid * 4);
    const float4 bb = *(const float4*)(b + (tid & 15) * 4);
    v.x += bb.x; v.y += bb.y; v.z += bb.z; v.w += bb.w;
    *(float4*)(z + (size_t)tid * 4) = v;
}

// ---- attention scores: s_i = tanh(z_i @ Wa^T + ba) . q + battn -------------
__global__ __launch_bounds__(256) void scores_kernel(const float* __restrict__ z,
                                                     const float* __restrict__ Wa,
                                                     const float* __restrict__ ba,
                                                     const float* __restrict__ q,
                                                     const float* __restrict__ battn,
                                                     float* __restrict__ scores,
                                                     float* __restrict__ blockmax, int N) {
    __shared__ float Wl[64 * 64];
    __shared__ float red[256];
    int t = threadIdx.x;
    for (int idx = t * 4; idx < 64 * 64; idx += 1024)
        *(float4*)(Wl + idx) = *(const float4*)(Wa + idx);
    __syncthreads();
    int i = blockIdx.x * 256 + t;
    float sc = -1e30f;
    if (i < N) {
        float zi[64];
#pragma unroll
        for (int kq = 0; kq < 16; kq++) {
            float4 v = *(const float4*)(z + (size_t)i * 64 + kq * 4);
            zi[kq * 4 + 0] = v.x; zi[kq * 4 + 1] = v.y;
            zi[kq * 4 + 2] = v.z; zi[kq * 4 + 3] = v.w;
        }
        float s = battn[0];
        for (int j = 0; j < 64; j++) {
            float tj = ba[j];
#pragma unroll
            for (int kq = 0; kq < 16; kq++) {
                float4 w4 = *(const float4*)(Wl + j * 64 + kq * 4);
                tj += zi[kq * 4 + 0] * w4.x + zi[kq * 4 + 1] * w4.y +
                      zi[kq * 4 + 2] * w4.z + zi[kq * 4 + 3] * w4.w;
            }
            s += tanhf(tj) * q[j];
        }
        scores[i] = s;
        sc = s;
    }
    red[t] = sc;
    __syncthreads();
    for (int off = 128; off > 0; off >>= 1) {
        if (t < off) red[t] = fmaxf(red[t], red[t + off]);
        __syncthreads();
    }
    if (t == 0) blockmax[blockIdx.x] = red[0];
}

__global__ void maxred_kernel(const float* __restrict__ blockmax,
                              float* __restrict__ smax, int NB) {
    __shared__ float red[512];
    int t = threadIdx.x;
    float v = (t < NB) ? blockmax[t] : -1e30f;
    for (int idx = t + 512; idx < NB; idx += 512) v = fmaxf(v, blockmax[idx]);
    red[t] = v;
    __syncthreads();
    for (int off = 256; off > 0; off >>= 1) {
        if (t < off) red[t] = fmaxf(red[t], red[t + off]);
        __syncthreads();
    }
    if (t == 0) *smax = red[0];
}

// ---- exp-sum and weighted feature sum --------------------------------------
// accum[0] = sum(exp(s_i - smax)); accum[1+f] = sum(exp(s_i - smax) * z[i][f])
__global__ __launch_bounds__(256) void expgc_kernel(const float* __restrict__ scores,
                                                    const float* __restrict__ z,
                                                    const float* __restrict__ smax,
                                                    float* __restrict__ accum, int N) {
    __shared__ float es[256];
    __shared__ float red[256];
    __shared__ float gp[4][64];
    int t = threadIdx.x;
    int base = blockIdx.x * 256;
    int i = base + t;
    float e = 0.f;
    if (i < N) e = expf(scores[i] - *smax);
    es[t] = e;
    red[t] = e;
    __syncthreads();
    for (int off = 128; off > 0; off >>= 1) {
        if (t < off) red[t] += red[t + off];
        __syncthreads();
    }
    if (t == 0) atomicAdd(&accum[0], red[0]);
    int f = t & 63, g = t >> 6;
    float a = 0.f;
    for (int n = 0; n < 64; n++) {
        int idx = base + g * 64 + n;
        if (idx < N) a += es[g * 64 + n] * z[(size_t)idx * 64 + f];
    }
    gp[g][f] = a;
    __syncthreads();
    if (g == 0) atomicAdd(&accum[1 + f], gp[0][f] + gp[1][f] + gp[2][f] + gp[3][f]);
}

__global__ void final_kernel(const float* __restrict__ accum, float* __restrict__ outg) {
    int t = threadIdx.x;
    if (t < 64) outg[t] = accum[1 + t] / accum[0];
}

// ---------------------------------------------------------------------------
extern "C" void kernel_launch(void* const* d_in, const int* in_sizes, int n_in,
                              void* d_out, int out_size, void* d_ws, size_t ws_size,
                              hipStream_t stream) {
    const float* x     = (const float*)d_in[0];
    const void*  ei    = d_in[1];
    const float* W1    = (const float*)d_in[2];
    const float* b1    = (const float*)d_in[3];
    const float* W2    = (const float*)d_in[4];
    const float* b2    = (const float*)d_in[5];
    const float* W3    = (const float*)d_in[6];
    const float* b3    = (const float*)d_in[7];
    const float* Wa    = (const float*)d_in[8];
    const float* ba    = (const float*)d_in[9];
    const float* q     = (const float*)d_in[10];
    const float* battn = (const float*)d_in[11];

    const int N = in_sizes[0] / 128;
    const int E = in_sizes[1] / 2;

    float* ws       = (float*)d_ws;
    float* dinv     = ws;                        // [N]
    float* H        = ws + N;                    // [N*64]
    float* scores   = H + (size_t)N * 64;        // [N]
    float* blockmax = scores + N;                // [<=512]
    float* accum    = blockmax + 512;            // [80]: 0=esum, 1..64=gc
    float* smax     = accum + 80;                // [1]
    int*   flag     = (int*)(smax + 4);          // [1]

    float* Z    = (float*)d_out;                 // [N,64]
    float* outg = Z + (size_t)N * 64;            // [64]

    hipMemsetAsync(dinv, 0, (size_t)N * sizeof(float), stream);
    hipMemsetAsync(accum, 0, 80 * sizeof(float), stream);

    detect_i64_kernel<<<1, 64, 0, stream>>>((const int*)ei, flag);
    deg_kernel<<<(E + 255) / 256, 256, 0, stream>>>(ei, flag, dinv, E);
    dinv_kernel<<<(N + 255) / 256, 256, 0, stream>>>(dinv, N);

    const int gb = (N + 63) / 64;
    const int sg = (int)(((long long)E * 16 + 255) / 256);
    const int nq = N * 16;
    const int ib = (nq + 255) / 256;
    const int NB = (N + 255) / 256;

    // layer 1: h1 = relu(agg(x@W1) + b1)   (relu+b fused into next GEMM load)
    gemm64<128, false><<<gb, 256, 0, stream>>>(x, W1, nullptr, H, N);
    initagg_kernel<<<ib, 256, 0, stream>>>(H, dinv, Z, nq);
    scatter_kernel<<<sg, 256, 0, stream>>>(H, dinv, ei, flag, Z, E);

    // layer 2
    gemm64<64, true><<<gb, 256, 0, stream>>>(Z, W2, b1, H, N);
    initagg_kernel<<<ib, 256, 0, stream>>>(H, dinv, Z, nq);
    scatter_kernel<<<sg, 256, 0, stream>>>(H, dinv, ei, flag, Z, E);

    // layer 3 (no relu on output)
    gemm64<64, true><<<gb, 256, 0, stream>>>(Z, W3, b2, H, N);
    initagg_kernel<<<ib, 256, 0, stream>>>(H, dinv, Z, nq);
    scatter_kernel<<<sg, 256, 0, stream>>>(H, dinv, ei, flag, Z, E);
    biasadd_kernel<<<ib, 256, 0, stream>>>(Z, b3, nq);

    // attention pooling
    scores_kernel<<<NB, 256, 0, stream>>>(Z, Wa, ba, q, battn, scores, blockmax, N);
    maxred_kernel<<<1, 512, 0, stream>>>(blockmax, smax, NB);
    expgc_kernel<<<NB, 256, 0, stream>>>(scores, Z, smax, accum, N);
    final_kernel<<<1, 64, 0, stream>>>(accum, outg);
}

// Round 2
// 632.388 us; speedup vs baseline: 6.8849x; 6.8849x over previous
//
#include <hip/hip_runtime.h>
#include <math.h>
#include <stdint.h>

// ---------------------------------------------------------------------------
// GCN (3 layers, PyG GCNConv w/ self-loops) + global attention pooling.
// N=100000 nodes, E=1600000 edges, D: 128 -> 64 -> 64 -> 64.
//
// Round 2: scatter-atomics (93% of time, 64x write amplification) replaced by
// CSR gather:
//   build    : int degree count -> 3-kernel prefix scan -> bucket edges into
//              csr[{src, w}] with per-dst cursors (one-time, ~1.6M atomics)
//   aggregate: one 64-lane wave per node, lane=feature; edges broadcast via
//              __shfl; acc += w * h[src][lane]; self-loop + bias fused.
//              Coalesced 256B reads, zero atomics, writes = 25.6MB exactly.
// ---------------------------------------------------------------------------

// ---- edge dtype detection (reference says int64; JAX w/o x64 gives int32) --
__global__ void detect_i64_kernel(const int* __restrict__ ei, int* __restrict__ flag) {
    if (threadIdx.x == 0 && blockIdx.x == 0) {
        int is64 = 1;
        for (int i = 1; i < 512; i += 2)
            if (ei[i] != 0) is64 = 0;
        *flag = is64;
    }
}

__device__ __forceinline__ void load_edge(const void* ei, int e, int E, int is64,
                                          int& s, int& d) {
    if (is64) {
        const long long* p = (const long long*)ei;
        s = (int)p[e]; d = (int)p[E + e];
    } else {
        const int* p = (const int*)ei;
        s = p[e]; d = p[E + e];
    }
}

// ---- degree count (int) ----------------------------------------------------
__global__ void count_kernel(const void* __restrict__ ei, const int* __restrict__ flag,
                             int* __restrict__ cnt, int E) {
    int e = blockIdx.x * 256 + threadIdx.x;
    if (e >= E) return;
    int is64 = *flag;
    int d;
    if (is64) d = (int)((const long long*)ei)[E + e];
    else      d = ((const int*)ei)[E + e];
    atomicAdd(&cnt[d], 1);
}

__global__ void dinv_kernel(const int* __restrict__ cnt, float* __restrict__ dinv, int N) {
    int i = blockIdx.x * 256 + threadIdx.x;
    if (i < N) dinv[i] = rsqrtf((float)cnt[i] + 1.0f);
}

// ---- prefix scan (3 kernels): cnt[N] -> exclusive rowptr[N+1] --------------
__global__ __launch_bounds__(1024) void scan1_kernel(const int* __restrict__ cnt,
                                                     int* __restrict__ part,
                                                     int* __restrict__ bsum, int N) {
    __shared__ int s[1024];
    int t = threadIdx.x;
    int i = blockIdx.x * 1024 + t;
    int v = (i < N) ? cnt[i] : 0;
    s[t] = v;
    __syncthreads();
    for (int off = 1; off < 1024; off <<= 1) {
        int x = (t >= off) ? s[t - off] : 0;
        __syncthreads();
        s[t] += x;
        __syncthreads();
    }
    if (i < N) part[i] = s[t] - v;          // exclusive within block
    if (t == 1023) bsum[blockIdx.x] = s[t]; // block total
}

__global__ __launch_bounds__(1024) void scan2_kernel(const int* __restrict__ bsum,
                                                     int* __restrict__ boff, int nb) {
    __shared__ int s[1024];
    int t = threadIdx.x;
    int v = (t < nb) ? bsum[t] : 0;
    s[t] = v;
    __syncthreads();
    for (int off = 1; off < 1024; off <<= 1) {
        int x = (t >= off) ? s[t - off] : 0;
        __syncthreads();
        s[t] += x;
        __syncthreads();
    }
    if (t < nb) boff[t] = s[t] - v;         // exclusive
}

__global__ void scan3_kernel(const int* __restrict__ part, const int* __restrict__ boff,
                             int* __restrict__ rowptr, int* __restrict__ cursor,
                             int N, int E) {
    int i = blockIdx.x * 256 + threadIdx.x;
    if (i < N) {
        int v = part[i] + boff[i >> 10];
        rowptr[i] = v;
        cursor[i] = v;
    }
    if (i == 0) rowptr[N] = E;
}

// ---- bucket edges into CSR: csr[pos] = {src, w} ----------------------------
__global__ void fill_kernel(const void* __restrict__ ei, const int* __restrict__ flag,
                            const float* __restrict__ dinv, int* __restrict__ cursor,
                            int2* __restrict__ csr, int E) {
    int e = blockIdx.x * 256 + threadIdx.x;
    if (e >= E) return;
    int s, d;
    load_edge(ei, e, E, *flag, s, d);
    float w = dinv[s] * dinv[d];
    int pos = atomicAdd(&cursor[d], 1);
    csr[pos] = make_int2(s, __float_as_int(w));
}

// ---- GEMM: out[N,64] = act(in[N,K]) @ W[K,64] ------------------------------
template <int K, bool PRE>
__global__ __launch_bounds__(256) void gemm64(const float* __restrict__ in,
                                              const float* __restrict__ Wg,
                                              const float* __restrict__ bias,
                                              float* __restrict__ out, int nrows) {
    constexpr int KQ = K / 4;
    __shared__ float Al[64 * K];
    __shared__ float Wt[64 * K];
    const int t  = threadIdx.x;
    const int rb = blockIdx.x * 64;

    for (int qidx = t; qidx < K * 16; qidx += 256) {
        int k  = qidx >> 4;
        int c0 = (qidx & 15) << 2;
        float4 v = *(const float4*)(Wg + k * 64 + c0);
        float vv[4] = {v.x, v.y, v.z, v.w};
#pragma unroll
        for (int j = 0; j < 4; j++) {
            int c  = c0 + j;
            int kq = (k >> 2) ^ ((c >> 2) & 7);
            Wt[(c * KQ + kq) * 4 + (k & 3)] = vv[j];
        }
    }
    for (int qidx = t; qidx < 64 * KQ; qidx += 256) {
        int r  = qidx / KQ;
        int kc = qidx % KQ;
        float4 v = make_float4(0.f, 0.f, 0.f, 0.f);
        int gr = rb + r;
        if (gr < nrows) v = *(const float4*)(in + (size_t)gr * K + (kc << 2));
        if (PRE) {
            v.x = fmaxf(v.x + bias[(kc << 2) + 0], 0.f);
            v.y = fmaxf(v.y + bias[(kc << 2) + 1], 0.f);
            v.z = fmaxf(v.z + bias[(kc << 2) + 2], 0.f);
            v.w = fmaxf(v.w + bias[(kc << 2) + 3], 0.f);
        }
        int sq = r * KQ + (kc ^ (r & 7));
        *(float4*)(&Al[sq * 4]) = v;
    }
    __syncthreads();

    const int tc = t & 15;
    const int tr = t >> 4;
    float acc[4][4];
#pragma unroll
    for (int i = 0; i < 4; i++)
#pragma unroll
        for (int j = 0; j < 4; j++) acc[i][j] = 0.f;

    for (int kb = 0; kb < KQ; ++kb) {
        float4 a[4], w[4];
#pragma unroll
        for (int i = 0; i < 4; i++) {
            int r = tr * 4 + i;
            a[i] = *(const float4*)(&Al[(r * KQ + (kb ^ (r & 7))) * 4]);
        }
#pragma unroll
        for (int j = 0; j < 4; j++) {
            int c = tc * 4 + j;
            w[j] = *(const float4*)(&Wt[(c * KQ + (kb ^ ((c >> 2) & 7))) * 4]);
        }
#pragma unroll
        for (int i = 0; i < 4; i++)
#pragma unroll
            for (int j = 0; j < 4; j++)
                acc[i][j] += a[i].x * w[j].x + a[i].y * w[j].y +
                             a[i].z * w[j].z + a[i].w * w[j].w;
    }
#pragma unroll
    for (int i = 0; i < 4; i++) {
        int r = rb + tr * 4 + i;
        if (r < nrows) {
            float4 o = make_float4(acc[i][0], acc[i][1], acc[i][2], acc[i][3]);
            *(float4*)(out + (size_t)r * 64 + tc * 4) = o;
        }
    }
}

// ---- CSR gather aggregation: one wave per node, lane = feature -------------
// out[i][f] = dinv[i]^2*h[i][f] + sum_{e in CSR[i]} w_e * h[src_e][f] (+bias)
template <bool BIAS>
__global__ __launch_bounds__(256) void gather64(const float* __restrict__ h,
                                                const float* __restrict__ dinv,
                                                const int* __restrict__ rowptr,
                                                const int2* __restrict__ csr,
                                                const float* __restrict__ bias,
                                                float* __restrict__ out, int N) {
    int gtid = blockIdx.x * 256 + threadIdx.x;
    int node = gtid >> 6;
    int lane = threadIdx.x & 63;
    if (node >= N) return;
    float di  = dinv[node];
    float acc = h[(size_t)node * 64 + lane] * di * di;
    int p0 = rowptr[node], p1 = rowptr[node + 1];
    for (int base = p0; base < p1; base += 64) {
        int me = base + lane;
        int2 ed = (me < p1) ? csr[me] : make_int2(0, 0);
        int kcnt = min(64, p1 - base);
        for (int j = 0; j < kcnt; ++j) {
            int   s = __shfl(ed.x, j);
            float w = __int_as_float(__shfl(ed.y, j));
            acc = fmaf(w, h[(size_t)s * 64 + lane], acc);
        }
    }
    if (BIAS) acc += bias[lane];
    out[(size_t)node * 64 + lane] = acc;
}

// ---- attention scores: s_i = tanh(z_i @ Wa^T + ba) . q + battn -------------
__global__ __launch_bounds__(256) void scores_kernel(const float* __restrict__ z,
                                                     const float* __restrict__ Wa,
                                                     const float* __restrict__ ba,
                                                     const float* __restrict__ q,
                                                     const float* __restrict__ battn,
                                                     float* __restrict__ scores,
                                                     float* __restrict__ blockmax, int N) {
    __shared__ float Wl[64 * 64];
    __shared__ float red[256];
    int t = threadIdx.x;
    for (int idx = t * 4; idx < 64 * 64; idx += 1024)
        *(float4*)(Wl + idx) = *(const float4*)(Wa + idx);
    __syncthreads();
    int i = blockIdx.x * 256 + t;
    float sc = -1e30f;
    if (i < N) {
        float zi[64];
#pragma unroll
        for (int kq = 0; kq < 16; kq++) {
            float4 v = *(const float4*)(z + (size_t)i * 64 + kq * 4);
            zi[kq * 4 + 0] = v.x; zi[kq * 4 + 1] = v.y;
            zi[kq * 4 + 2] = v.z; zi[kq * 4 + 3] = v.w;
        }
        float s = battn[0];
        for (int j = 0; j < 64; j++) {
            float tj = ba[j];
#pragma unroll
            for (int kq = 0; kq < 16; kq++) {
                float4 w4 = *(const float4*)(Wl + j * 64 + kq * 4);
                tj += zi[kq * 4 + 0] * w4.x + zi[kq * 4 + 1] * w4.y +
                      zi[kq * 4 + 2] * w4.z + zi[kq * 4 + 3] * w4.w;
            }
            s += tanhf(tj) * q[j];
        }
        scores[i] = s;
        sc = s;
    }
    red[t] = sc;
    __syncthreads();
    for (int off = 128; off > 0; off >>= 1) {
        if (t < off) red[t] = fmaxf(red[t], red[t + off]);
        __syncthreads();
    }
    if (t == 0) blockmax[blockIdx.x] = red[0];
}

__global__ void maxred_kernel(const float* __restrict__ blockmax,
                              float* __restrict__ smax, int NB) {
    __shared__ float red[512];
    int t = threadIdx.x;
    float v = (t < NB) ? blockmax[t] : -1e30f;
    for (int idx = t + 512; idx < NB; idx += 512) v = fmaxf(v, blockmax[idx]);
    red[t] = v;
    __syncthreads();
    for (int off = 256; off > 0; off >>= 1) {
        if (t < off) red[t] = fmaxf(red[t], red[t + off]);
        __syncthreads();
    }
    if (t == 0) *smax = red[0];
}

// accum[0] = sum(exp(s_i - smax)); accum[1+f] = sum(exp(s_i - smax) * z[i][f])
__global__ __launch_bounds__(256) void expgc_kernel(const float* __restrict__ scores,
                                                    const float* __restrict__ z,
                                                    const float* __restrict__ smax,
                                                    float* __restrict__ accum, int N) {
    __shared__ float es[256];
    __shared__ float red[256];
    __shared__ float gp[4][64];
    int t = threadIdx.x;
    int base = blockIdx.x * 256;
    int i = base + t;
    float e = 0.f;
    if (i < N) e = expf(scores[i] - *smax);
    es[t] = e;
    red[t] = e;
    __syncthreads();
    for (int off = 128; off > 0; off >>= 1) {
        if (t < off) red[t] += red[t + off];
        __syncthreads();
    }
    if (t == 0) atomicAdd(&accum[0], red[0]);
    int f = t & 63, g = t >> 6;
    float a = 0.f;
    for (int n = 0; n < 64; n++) {
        int idx = base + g * 64 + n;
        if (idx < N) a += es[g * 64 + n] * z[(size_t)idx * 64 + f];
    }
    gp[g][f] = a;
    __syncthreads();
    if (g == 0) atomicAdd(&accum[1 + f], gp[0][f] + gp[1][f] + gp[2][f] + gp[3][f]);
}

__global__ void final_kernel(const float* __restrict__ accum, float* __restrict__ outg) {
    int t = threadIdx.x;
    if (t < 64) outg[t] = accum[1 + t] / accum[0];
}

// ---------------------------------------------------------------------------
extern "C" void kernel_launch(void* const* d_in, const int* in_sizes, int n_in,
                              void* d_out, int out_size, void* d_ws, size_t ws_size,
                              hipStream_t stream) {
    const float* x     = (const float*)d_in[0];
    const void*  ei    = d_in[1];
    const float* W1    = (const float*)d_in[2];
    const float* b1    = (const float*)d_in[3];
    const float* W2    = (const float*)d_in[4];
    const float* b2    = (const float*)d_in[5];
    const float* W3    = (const float*)d_in[6];
    const float* b3    = (const float*)d_in[7];
    const float* Wa    = (const float*)d_in[8];
    const float* ba    = (const float*)d_in[9];
    const float* q     = (const float*)d_in[10];
    const float* battn = (const float*)d_in[11];

    const int N = in_sizes[0] / 128;
    const int E = in_sizes[1] / 2;

    float* ws       = (float*)d_ws;
    float* dinv     = ws;                        // [N]
    float* H        = ws + N;                    // [N*64]
    float* scores   = H + (size_t)N * 64;        // [N]
    float* blockmax = scores + N;                // [512]
    float* accum    = blockmax + 512;            // [80]
    float* smax     = accum + 80;                // [4]
    int*   flag     = (int*)(smax + 4);          // [4]
    int*   cnt      = flag + 4;                  // [N]
    int*   rowptr   = cnt + N;                   // [N+1]
    int*   cursor   = rowptr + N + 1;            // [N]
    int*   part     = cursor + N;                // [N]
    int*   bsum     = part + N;                  // [1024]
    int*   boff     = bsum + 1024;               // [1024]
    int2*  csr      = (int2*)((((uintptr_t)(boff + 1024)) + 15) & ~(uintptr_t)15); // [E]

    float* Z    = (float*)d_out;                 // [N,64]
    float* outg = Z + (size_t)N * 64;            // [64]

    hipMemsetAsync(cnt, 0, (size_t)N * sizeof(int), stream);
    hipMemsetAsync(accum, 0, 80 * sizeof(float), stream);

    detect_i64_kernel<<<1, 64, 0, stream>>>((const int*)ei, flag);
    count_kernel<<<(E + 255) / 256, 256, 0, stream>>>(ei, flag, cnt, E);
    dinv_kernel<<<(N + 255) / 256, 256, 0, stream>>>(cnt, dinv, N);

    const int nb = (N + 1023) / 1024;
    scan1_kernel<<<nb, 1024, 0, stream>>>(cnt, part, bsum, N);
    scan2_kernel<<<1, 1024, 0, stream>>>(bsum, boff, nb);
    scan3_kernel<<<(N + 255) / 256, 256, 0, stream>>>(part, boff, rowptr, cursor, N, E);
    fill_kernel<<<(E + 255) / 256, 256, 0, stream>>>(ei, flag, dinv, cursor, csr, E);

    const int gb = (N + 63) / 64;
    const int ag = (int)(((long long)N * 64 + 255) / 256);
    const int NB = (N + 255) / 256;

    // layer 1: h1 = relu(agg(x@W1) + b1)   (relu+b fused into next GEMM load)
    gemm64<128, false><<<gb, 256, 0, stream>>>(x, W1, nullptr, H, N);
    gather64<false><<<ag, 256, 0, stream>>>(H, dinv, rowptr, csr, nullptr, Z, N);

    // layer 2
    gemm64<64, true><<<gb, 256, 0, stream>>>(Z, W2, b1, H, N);
    gather64<false><<<ag, 256, 0, stream>>>(H, dinv, rowptr, csr, nullptr, Z, N);

    // layer 3 (bias b3 fused into gather)
    gemm64<64, true><<<gb, 256, 0, stream>>>(Z, W3, b2, H, N);
    gather64<true><<<ag, 256, 0, stream>>>(H, dinv, rowptr, csr, b3, Z, N);

    // attention pooling
    scores_kernel<<<NB, 256, 0, stream>>>(Z, Wa, ba, q, battn, scores, blockmax, N);
    maxred_kernel<<<1, 512, 0, stream>>>(blockmax, smax, NB);
    expgc_kernel<<<NB, 256, 0, stream>>>(scores, Z, smax, accum, N);
    final_kernel<<<1, 64, 0, stream>>>(accum, outg);
}